// Round 1
// baseline (10149.045 us; speedup 1.0000x reference)
//
#include <hip/hip_runtime.h>
#include <cfloat>
#include <cmath>

#define NB 128
#define NL 48
#define HID 512
#define NSLOT 48
#define K2ROWS (NB*2)
#define AROWS (NB*(NL-1))   // 6016

// ---------------- workspace layout (float units) ----------------
static const size_t offH    = 0;                                   // [B][48][512]
static const size_t offC    = offH  + (size_t)NB*NSLOT*HID;
static const size_t offCH   = offC  + (size_t)NB*NSLOT*HID;        // candidate h
static const size_t offCC   = offCH + (size_t)NB*NSLOT*HID;        // candidate c
static const size_t offLG   = offCC + (size_t)NB*NSLOT*HID;        // logits [B][48]
static const size_t offNXT  = offLG  + (size_t)NB*NSLOT;           // int
static const size_t offPRV  = offNXT + (size_t)NB*NSLOT;           // int
static const size_t offROWS = offPRV + (size_t)NB*NSLOT;           // int4 x 256
static const size_t offROWSA= offROWS + (size_t)4*K2ROWS;          // int4 x 6016
// total ~50.5 MB

__device__ __forceinline__ float sigf(float x){ return 1.0f/(1.0f+expf(-x)); }

// ---------------- init: copy input -> H,C ; init links/logits ----------------
__global__ void k_init(const float* __restrict__ in, const int* __restrict__ len,
                       float* __restrict__ H, float* __restrict__ Cc,
                       float* __restrict__ LG, int* __restrict__ NXT,
                       int* __restrict__ PRV, int4* __restrict__ ROWS)
{
    int bs = blockIdx.x;            // b*48+s
    int b  = bs / NSLOT, s = bs % NSLOT;
    int t  = threadIdx.x;           // 256 threads, 1 float4 each
    const float4* inrow = (const float4*)(in + (size_t)bs*2*HID);
    float4 v = inrow[t];
    if (t < 128) ((float4*)(H  + (size_t)bs*HID))[t]       = v;
    else         ((float4*)(Cc + (size_t)bs*HID))[t - 128] = v;
    if (t == 0) {
        int lb = len[b];
        NXT[bs] = (s+1 < lb) ? s+1 : -1;
        PRV[bs] = (s > 0 && s < lb) ? s-1 : -1;
        LG[bs]  = -FLT_MAX;
        if (s == 0) {
            ROWS[b*2+0] = make_int4(0,0,0,-1);
            ROWS[b*2+1] = make_int4(0,0,0,-1);
        }
    }
}

// ---------------- phase-A row descriptors ----------------
__global__ void k_descA(const int* __restrict__ len, int4* __restrict__ ROWSA)
{
    int r = blockIdx.x*256 + threadIdx.x;
    if (r >= AROWS) return;
    int b = r/(NL-1), s = r%(NL-1);
    int lb = len[b];
    ROWSA[r] = make_int4(b, s, s+1, (s <= lb-2) ? s : -1);
}

// ---------------- compose GEMM + LSTM epilogue ----------------
// rows: int4 {b, sl, sr, dst(-1=invalid)}. v[n] = sum_k [h_sl||h_sr][k]*W[n][k]+b[n]
// thread map: tt = tid&15 -> t-column, mg = tid>>4 -> AM rows. grid.y = 32 t-tiles.
template<int AM>
__global__ __launch_bounds__(256, 2)
void k_compose(const int4* __restrict__ rows, int nrows,
               const float* __restrict__ H, const float* __restrict__ Cc,
               float* __restrict__ CH, float* __restrict__ CC,
               const float* __restrict__ W, const float* __restrict__ bias)
{
    int tt = threadIdx.x & 15, mg = threadIdx.x >> 4;
    int tcol = blockIdx.y*16 + tt;            // 0..511
    float acc[AM][5];
    const float* bl[AM]; const float* br[AM];
    int4 rd[AM];
    int rbase = blockIdx.x*(16*AM) + mg*AM;
    for (int am=0; am<AM; ++am){
        int r = rbase + am;
        rd[am] = (r < nrows) ? rows[r] : make_int4(0,0,0,-1);
        int b = rd[am].x, sl = rd[am].y, sr = rd[am].z;
        if (rd[am].w < 0){ b = 0; sl = 0; sr = 0; }
        bl[am] = H + (size_t)(b*NSLOT+sl)*HID;
        br[am] = H + (size_t)(b*NSLOT+sr)*HID;
        for (int j=0;j<5;++j) acc[am][j]=0.f;
    }
    const float* wb[5];
    for (int j=0;j<5;++j) wb[j] = W + (size_t)(j*HID + tcol)*1024;

    #pragma unroll 4
    for (int k=0; k<HID; k+=4){               // K first half: left node
        float4 wv[5];
        for (int j=0;j<5;++j) wv[j] = *(const float4*)(wb[j] + k);
        for (int am=0; am<AM; ++am){
            float4 xv = *(const float4*)(bl[am] + k);
            for (int j=0;j<5;++j){
                acc[am][j] = fmaf(xv.x, wv[j].x, acc[am][j]);
                acc[am][j] = fmaf(xv.y, wv[j].y, acc[am][j]);
                acc[am][j] = fmaf(xv.z, wv[j].z, acc[am][j]);
                acc[am][j] = fmaf(xv.w, wv[j].w, acc[am][j]);
            }
        }
    }
    #pragma unroll 4
    for (int k=0; k<HID; k+=4){               // K second half: right node
        float4 wv[5];
        for (int j=0;j<5;++j) wv[j] = *(const float4*)(wb[j] + HID + k);
        for (int am=0; am<AM; ++am){
            float4 xv = *(const float4*)(br[am] + k);
            for (int j=0;j<5;++j){
                acc[am][j] = fmaf(xv.x, wv[j].x, acc[am][j]);
                acc[am][j] = fmaf(xv.y, wv[j].y, acc[am][j]);
                acc[am][j] = fmaf(xv.z, wv[j].z, acc[am][j]);
                acc[am][j] = fmaf(xv.w, wv[j].w, acc[am][j]);
            }
        }
    }
    for (int am=0; am<AM; ++am){
        if (rd[am].w < 0) continue;
        int b = rd[am].x, sl = rd[am].y, sr = rd[am].z, dst = rd[am].w;
        float vi  = acc[am][0] + bias[0*HID + tcol];
        float vfl = acc[am][1] + bias[1*HID + tcol];
        float vfr = acc[am][2] + bias[2*HID + tcol];
        float vu  = acc[am][3] + bias[3*HID + tcol];
        float vo  = acc[am][4] + bias[4*HID + tcol];
        float cl = Cc[(size_t)(b*NSLOT+sl)*HID + tcol];
        float cr = Cc[(size_t)(b*NSLOT+sr)*HID + tcol];
        float cn = cl*sigf(vfl+1.f) + cr*sigf(vfr+1.f) + tanhf(vu)*sigf(vi);
        float hn = sigf(vo)*tanhf(cn);
        CH[(size_t)(b*NSLOT+dst)*HID + tcol] = hn;
        CC[(size_t)(b*NSLOT+dst)*HID + tcol] = cn;
    }
}

// ---------------- logits for phase A (one wave per row) ----------------
__global__ void k_logitA(const float* __restrict__ CH, const float* __restrict__ q,
                         const int* __restrict__ len, float* __restrict__ LG)
{
    int w = threadIdx.x >> 6, lane = threadIdx.x & 63;
    int r = blockIdx.x*4 + w;
    if (r >= AROWS) return;
    int b = r/(NL-1), s = r%(NL-1);
    if (s > len[b]-2) return;
    const float* h = CH + (size_t)(b*NSLOT+s)*HID;
    float sum = 0.f;
    #pragma unroll
    for (int e=0;e<8;++e) sum += h[lane*8+e]*q[lane*8+e];
    for (int off=32; off; off>>=1) sum += __shfl_xor(sum, off);
    if (lane==0) LG[b*NSLOT+s] = sum;
}

// ---------------- per-step: finalize logits, argmax, merge bookkeeping ----------------
__global__ void k_step(int i, const int* __restrict__ len,
                       float* __restrict__ H, float* __restrict__ Cc,
                       const float* __restrict__ CH, const float* __restrict__ CC,
                       float* __restrict__ LG, int* __restrict__ NXT,
                       int* __restrict__ PRV, int4* __restrict__ ROWS,
                       const float* __restrict__ q)
{
    int b = blockIdx.x, lane = threadIdx.x;   // block = 64 = 1 wave
    int base = b*NSLOT;

    // phase 0: finalize logits of previous step's refreshed candidates
    int d0 = -1, d1 = -1; float s0 = 0.f, s1 = 0.f;
    if (i > 0){
        for (int e=0;e<2;++e){
            int4 rd = ROWS[b*2+e];
            if (rd.w < 0) continue;
            const float* h = CH + (size_t)(base+rd.w)*HID;
            float sum = 0.f;
            #pragma unroll
            for (int t=0;t<8;++t) sum += h[lane*8+t]*q[lane*8+t];
            for (int off=32; off; off>>=1) sum += __shfl_xor(sum, off);
            if (lane==0) LG[base+rd.w] = sum;        // persist for future steps
            if (e==0){ d0 = rd.w; s0 = sum; } else { d1 = rd.w; s1 = sum; }
        }
    }

    // phase 1: active?
    int lb = len[b];
    if (i > lb-2){
        if (lane==0){ ROWS[b*2+0]=make_int4(0,0,0,-1); ROWS[b*2+1]=make_int4(0,0,0,-1); }
        return;
    }

    // phase 2: argmax over slots (first-max => smallest slot on tie)
    float val = (lane < NSLOT) ? LG[base+lane] : -FLT_MAX;
    if (lane == d0) val = s0;
    if (lane == d1) val = s1;
    int idx = lane;
    for (int off=1; off<64; off<<=1){
        float oval = __shfl_xor(val, off);
        int   oidx = __shfl_xor(idx, off);
        if (oval > val || (oval == val && oidx < idx)){ val = oval; idx = oidx; }
    }
    int sstar = idx;
    int r  = NXT[base+sstar];
    int qn = NXT[base+r];
    int p  = PRV[base+sstar];

    // phase 3: commit merged node into left child's slot
    const float4* sh = (const float4*)(CH + (size_t)(base+sstar)*HID);
    const float4* sc = (const float4*)(CC + (size_t)(base+sstar)*HID);
    float4* dh = (float4*)(H  + (size_t)(base+sstar)*HID);
    float4* dc = (float4*)(Cc + (size_t)(base+sstar)*HID);
    dh[lane] = sh[lane]; dh[lane+64] = sh[lane+64];
    dc[lane] = sc[lane]; dc[lane+64] = sc[lane+64];

    // phase 4: relink + invalidate + emit refresh rows
    if (lane==0){
        NXT[base+sstar] = qn;
        if (qn >= 0) PRV[base+qn] = sstar;
        LG[base+r] = -FLT_MAX;                      // removed right child's pair
        if (qn < 0) LG[base+sstar] = -FLT_MAX;      // no pair to the right anymore
        ROWS[b*2+0] = (p  >= 0) ? make_int4(b, p, sstar, p)      : make_int4(0,0,0,-1);
        ROWS[b*2+1] = (qn >= 0) ? make_int4(b, sstar, qn, sstar) : make_int4(0,0,0,-1);
    }
}

// ---------------- output: root = slot 0 ----------------
__global__ void k_out(const float* __restrict__ H, float* __restrict__ out)
{
    int b = blockIdx.x, t = threadIdx.x;       // 128 threads x float4
    ((float4*)out)[b*128 + t] = ((const float4*)(H + (size_t)b*NSLOT*HID))[t];
}

extern "C" void kernel_launch(void* const* d_in, const int* in_sizes, int n_in,
                              void* d_out, int out_size, void* d_ws, size_t ws_size,
                              hipStream_t stream)
{
    const float* in   = (const float*)d_in[0];
    const float* W    = (const float*)d_in[1];
    const float* bias = (const float*)d_in[2];
    const float* q    = (const float*)d_in[3];
    const int*   len  = (const int*)d_in[4];

    float* ws = (float*)d_ws;
    float* H  = ws + offH;
    float* Cc = ws + offC;
    float* CH = ws + offCH;
    float* CC = ws + offCC;
    float* LG = ws + offLG;
    int* NXT  = (int*)(ws + offNXT);
    int* PRV  = (int*)(ws + offPRV);
    int4* ROWS  = (int4*)(ws + offROWS);
    int4* ROWSA = (int4*)(ws + offROWSA);
    float* out = (float*)d_out;

    k_init <<<dim3(NB*NSLOT), dim3(256), 0, stream>>>(in, len, H, Cc, LG, NXT, PRV, ROWS);
    k_descA<<<dim3((AROWS+255)/256), dim3(256), 0, stream>>>(len, ROWSA);
    // phase A: all 47 initial candidates  (M=6016, K=1024, N=2560)
    k_compose<4><<<dim3(AROWS/64, 32), dim3(256), 0, stream>>>(ROWSA, AROWS, H, Cc, CH, CC, W, bias);
    k_logitA<<<dim3(AROWS/4), dim3(256), 0, stream>>>(CH, q, len, LG);

    for (int i = 0; i < NL-1; ++i){
        k_step<<<dim3(NB), dim3(64), 0, stream>>>(i, len, H, Cc, CH, CC, LG, NXT, PRV, ROWS, q);
        if (i < NL-2)
            k_compose<2><<<dim3(K2ROWS/32, 32), dim3(256), 0, stream>>>(ROWS, K2ROWS, H, Cc, CH, CC, W, bias);
    }
    k_out<<<dim3(NB), dim3(128), 0, stream>>>(H, out);
}

// Round 2
// 2360.194 us; speedup vs baseline: 4.3001x; 4.3001x over previous
//
#include <hip/hip_runtime.h>
#include <cfloat>
#include <cmath>

#define NB 128
#define NL 48
#define HID 512
#define NSLOT 48
#define NN 2560              // 5*HID output cols
#define AROWS (NB*(NL-1))    // 6016 phase-A pair rows
#define SROWS (NB*2)         // 256 per-step refresh rows

// ---------------- workspace layout (float units) ----------------
static const size_t offH    = 0;                                   // [B][48][512]
static const size_t offC    = offH  + (size_t)NB*NSLOT*HID;
static const size_t offCH   = offC  + (size_t)NB*NSLOT*HID;        // candidate h
static const size_t offCC   = offCH + (size_t)NB*NSLOT*HID;        // candidate c
static const size_t offLG   = offCC + (size_t)NB*NSLOT*HID;        // logits [B][48]
static const size_t offNXT  = offLG  + (size_t)NB*NSLOT;           // int
static const size_t offPRV  = offNXT + (size_t)NB*NSLOT;           // int
static const size_t offROWS = offPRV + (size_t)NB*NSLOT;           // int4 x 256
static const size_t offROWSA= offROWS + (size_t)4*SROWS;           // int4 x 6016
static const size_t offV    = offROWSA + (size_t)4*AROWS;          // float x 3072*2560 (31.5MB)
// total ~82 MB

__device__ __forceinline__ float sigf(float x){ return 1.0f/(1.0f+expf(-x)); }

// ---------------- init: copy input -> H,C ; init links/logits ----------------
__global__ void k_init(const float* __restrict__ in, const int* __restrict__ len,
                       float* __restrict__ H, float* __restrict__ Cc,
                       float* __restrict__ LG, int* __restrict__ NXT,
                       int* __restrict__ PRV, int4* __restrict__ ROWS)
{
    int bs = blockIdx.x;            // b*48+s
    int b  = bs / NSLOT, s = bs % NSLOT;
    int t  = threadIdx.x;           // 256 threads, 1 float4 each
    const float4* inrow = (const float4*)(in + (size_t)bs*2*HID);
    float4 v = inrow[t];
    if (t < 128) ((float4*)(H  + (size_t)bs*HID))[t]       = v;
    else         ((float4*)(Cc + (size_t)bs*HID))[t - 128] = v;
    if (t == 0) {
        int lb = len[b];
        NXT[bs] = (s+1 < lb) ? s+1 : -1;
        PRV[bs] = (s > 0 && s < lb) ? s-1 : -1;
        LG[bs]  = -FLT_MAX;
        if (s == 0) {
            ROWS[b*2+0] = make_int4(0,0,0,-1);
            ROWS[b*2+1] = make_int4(0,0,0,-1);
        }
    }
}

// ---------------- phase-A row descriptors ----------------
__global__ void k_descA(const int* __restrict__ len, int4* __restrict__ ROWSA)
{
    int r = blockIdx.x*256 + threadIdx.x;
    if (r >= AROWS) return;
    int b = r/(NL-1), s = r%(NL-1);
    int lb = len[b];
    ROWSA[r] = make_int4(b, s, s+1, (s <= lb-2) ? s : -1);
}

// ---------------- tiled SGEMM-TN with gathered A rows ----------------
// out[(kz*M + row)*2560 + n] = sum_{k in [kz*KT*16, (kz+1)*KT*16)} x_row[k] * W[n][k]
// x_row = concat(H[b,sl], H[b,sr]) per descriptor. BN=64, BK=16, 256 threads.
// MI=8 -> BM=128 (8x4 micro). MI=4 -> BM=64 (4x4 micro).
template<int MI, int KT>
__global__ __launch_bounds__(256, 2)
void k_gemm(const int4* __restrict__ rows, int M,
            const float* __restrict__ H, const float* __restrict__ W,
            float* __restrict__ out)
{
    constexpr int BM  = 16*MI;
    constexpr int AF4 = BM/64;        // float4s per thread for A staging
    constexpr int LDA = BM + 4;       // pad: 16B-aligned, <=2-way bank conflicts
    constexpr int LDB = 68;
    __shared__ float As[2][16*LDA];
    __shared__ float Bs[2][16*LDB];

    const int t  = threadIdx.x;
    const int m0 = blockIdx.x*BM;
    const int n0 = blockIdx.y*64;
    const int kz = blockIdx.z;
    const int kg0 = kz*KT*16;

    // A staging map: float4 f -> row=f>>2, kseg=f&3
    int aoffL[AF4], aoffR[AF4], arow[AF4], aseg[AF4];
    #pragma unroll
    for (int j=0;j<AF4;++j){
        int f = t*AF4 + j;
        arow[j] = f >> 2; aseg[j] = f & 3;
        int4 rd = rows[m0 + arow[j]];
        aoffL[j] = (rd.x*NSLOT + rd.y)*HID + aseg[j]*4;
        aoffR[j] = (rd.x*NSLOT + rd.z)*HID + aseg[j]*4;
    }
    // B staging map
    const int brow = t >> 2, bseg = t & 3;
    const float* wptr = W + (size_t)(n0 + brow)*1024 + bseg*4;

    const int tm = t >> 4, tn = t & 15;

    float acc[MI][4];
    #pragma unroll
    for (int mi=0;mi<MI;++mi)
        #pragma unroll
        for (int j=0;j<4;++j) acc[mi][j]=0.f;

    float4 av[AF4], bv;
    auto gload = [&](int kt){
        int kg = kg0 + kt*16;
        int sideR = (kg >> 9) & 1;
        int ke = kg & 511;
        #pragma unroll
        for (int j=0;j<AF4;++j)
            av[j] = *(const float4*)(H + (sideR ? aoffR[j] : aoffL[j]) + ke);
        bv = *(const float4*)(wptr + kg);
    };
    auto swrite = [&](int buf){
        #pragma unroll
        for (int j=0;j<AF4;++j){
            As[buf][(aseg[j]*4+0)*LDA + arow[j]] = av[j].x;
            As[buf][(aseg[j]*4+1)*LDA + arow[j]] = av[j].y;
            As[buf][(aseg[j]*4+2)*LDA + arow[j]] = av[j].z;
            As[buf][(aseg[j]*4+3)*LDA + arow[j]] = av[j].w;
        }
        Bs[buf][(bseg*4+0)*LDB + brow] = bv.x;
        Bs[buf][(bseg*4+1)*LDB + brow] = bv.y;
        Bs[buf][(bseg*4+2)*LDB + brow] = bv.z;
        Bs[buf][(bseg*4+3)*LDB + brow] = bv.w;
    };

    gload(0); swrite(0); __syncthreads();

    for (int kt=0; kt<KT; ++kt){
        int buf = kt & 1;
        if (kt+1 < KT) gload(kt+1);
        #pragma unroll
        for (int k=0;k<16;++k){
            float a[MI];
            #pragma unroll
            for (int mi=0;mi<MI;mi+=4){
                float4 a4 = *(const float4*)&As[buf][k*LDA + tm*MI + mi];
                a[mi]=a4.x; a[mi+1]=a4.y; a[mi+2]=a4.z; a[mi+3]=a4.w;
            }
            float4 b4 = *(const float4*)&Bs[buf][k*LDB + tn*4];
            #pragma unroll
            for (int mi=0;mi<MI;++mi){
                acc[mi][0] = fmaf(a[mi], b4.x, acc[mi][0]);
                acc[mi][1] = fmaf(a[mi], b4.y, acc[mi][1]);
                acc[mi][2] = fmaf(a[mi], b4.z, acc[mi][2]);
                acc[mi][3] = fmaf(a[mi], b4.w, acc[mi][3]);
            }
        }
        if (kt+1 < KT) swrite(buf^1);
        __syncthreads();
    }

    #pragma unroll
    for (int mi=0;mi<MI;++mi){
        int row = m0 + tm*MI + mi;
        float4 o; o.x=acc[mi][0]; o.y=acc[mi][1]; o.z=acc[mi][2]; o.w=acc[mi][3];
        *(float4*)(out + (size_t)(kz*M + row)*NN + n0 + tn*4) = o;
    }
}

// ---------------- combine partials + bias -> LSTM epilogue -> CH/CC + logit ----------------
__global__ void k_combine(const int4* __restrict__ rows, const float* __restrict__ V,
                          int KS, int M,
                          const float* __restrict__ Cc, const float* __restrict__ bias,
                          const float* __restrict__ q,
                          float* __restrict__ CH, float* __restrict__ CC,
                          float* __restrict__ LG)
{
    int r = blockIdx.x;
    int4 rd = rows[r];
    if (rd.w < 0) return;
    int t = threadIdx.x;
    int b = rd.x, sl = rd.y, sr = rd.z, dst = rd.w;
    const float* cl = Cc + (size_t)(b*NSLOT+sl)*HID;
    const float* cr = Cc + (size_t)(b*NSLOT+sr)*HID;
    float part = 0.f;
    #pragma unroll
    for (int h2=0; h2<2; ++h2){
        int c = t + h2*256;
        float v[5];
        #pragma unroll
        for (int g=0; g<5; ++g){
            float s = bias[g*HID + c];
            for (int kzi=0; kzi<KS; ++kzi)
                s += V[(size_t)(kzi*M + r)*NN + g*HID + c];
            v[g] = s;
        }
        float cn = cl[c]*sigf(v[1]+1.f) + cr[c]*sigf(v[2]+1.f) + tanhf(v[3])*sigf(v[0]);
        float hn = sigf(v[4])*tanhf(cn);
        CH[(size_t)(b*NSLOT+dst)*HID + c] = hn;
        CC[(size_t)(b*NSLOT+dst)*HID + c] = cn;
        part += q[c]*hn;
    }
    __shared__ float red[4];
    #pragma unroll
    for (int off=32; off; off>>=1) part += __shfl_xor(part, off);
    if ((t & 63) == 0) red[t>>6] = part;
    __syncthreads();
    if (t == 0) LG[b*NSLOT + dst] = red[0]+red[1]+red[2]+red[3];
}

// ---------------- per-step: argmax, commit, relink ----------------
__global__ void k_step(int i, const int* __restrict__ len,
                       float* __restrict__ H, float* __restrict__ Cc,
                       const float* __restrict__ CH, const float* __restrict__ CC,
                       float* __restrict__ LG, int* __restrict__ NXT,
                       int* __restrict__ PRV, int4* __restrict__ ROWS)
{
    int b = blockIdx.x, lane = threadIdx.x;   // block = 64 = 1 wave
    int base = b*NSLOT;
    int lb = len[b];
    if (i > lb-2){
        if (lane==0){ ROWS[b*2+0]=make_int4(0,0,0,-1); ROWS[b*2+1]=make_int4(0,0,0,-1); }
        return;
    }

    // argmax over slots (first-max => smallest slot on tie)
    float val = (lane < NSLOT) ? LG[base+lane] : -FLT_MAX;
    int idx = lane;
    for (int off=1; off<64; off<<=1){
        float oval = __shfl_xor(val, off);
        int   oidx = __shfl_xor(idx, off);
        if (oval > val || (oval == val && oidx < idx)){ val = oval; idx = oidx; }
    }
    int sstar = idx;
    int r  = NXT[base+sstar];
    int qn = NXT[base+r];
    int p  = PRV[base+sstar];

    // commit merged node into left child's slot
    const float4* sh = (const float4*)(CH + (size_t)(base+sstar)*HID);
    const float4* sc = (const float4*)(CC + (size_t)(base+sstar)*HID);
    float4* dh = (float4*)(H  + (size_t)(base+sstar)*HID);
    float4* dc = (float4*)(Cc + (size_t)(base+sstar)*HID);
    dh[lane] = sh[lane]; dh[lane+64] = sh[lane+64];
    dc[lane] = sc[lane]; dc[lane+64] = sc[lane+64];

    // relink + invalidate + emit refresh rows
    if (lane==0){
        NXT[base+sstar] = qn;
        if (qn >= 0) PRV[base+qn] = sstar;
        LG[base+r] = -FLT_MAX;                      // removed right child's pair
        if (qn < 0) LG[base+sstar] = -FLT_MAX;      // no pair to the right anymore
        ROWS[b*2+0] = (p  >= 0) ? make_int4(b, p, sstar, p)      : make_int4(0,0,0,-1);
        ROWS[b*2+1] = (qn >= 0) ? make_int4(b, sstar, qn, sstar) : make_int4(0,0,0,-1);
    }
}

// ---------------- output: root = slot 0 ----------------
__global__ void k_out(const float* __restrict__ H, float* __restrict__ out)
{
    int b = blockIdx.x, t = threadIdx.x;       // 128 threads x float4
    ((float4*)out)[b*128 + t] = ((const float4*)(H + (size_t)b*NSLOT*HID))[t];
}

extern "C" void kernel_launch(void* const* d_in, const int* in_sizes, int n_in,
                              void* d_out, int out_size, void* d_ws, size_t ws_size,
                              hipStream_t stream)
{
    const float* in   = (const float*)d_in[0];
    const float* W    = (const float*)d_in[1];
    const float* bias = (const float*)d_in[2];
    const float* q    = (const float*)d_in[3];
    const int*   len  = (const int*)d_in[4];

    float* ws = (float*)d_ws;
    float* H  = ws + offH;
    float* Cc = ws + offC;
    float* CH = ws + offCH;
    float* CC = ws + offCC;
    float* LG = ws + offLG;
    int* NXT  = (int*)(ws + offNXT);
    int* PRV  = (int*)(ws + offPRV);
    int4* ROWS  = (int4*)(ws + offROWS);
    int4* ROWSA = (int4*)(ws + offROWSA);
    float* V  = ws + offV;
    float* out = (float*)d_out;

    k_init <<<dim3(NB*NSLOT), dim3(256), 0, stream>>>(in, len, H, Cc, LG, NXT, PRV, ROWS);
    k_descA<<<dim3((AROWS+255)/256), dim3(256), 0, stream>>>(len, ROWSA);

    // phase A in 2 M-chunks: GEMM (K=1024) -> V, then combine -> CH/CC/LG
    {
        int bases[3] = {0, 3072, AROWS};
        for (int c2 = 0; c2 < 2; ++c2){
            int base = bases[c2], Mc = bases[c2+1] - base;
            k_gemm<8,64><<<dim3(Mc/128, NN/64, 1), dim3(256), 0, stream>>>(
                ROWSA + base, Mc, H, W, V);
            k_combine<<<dim3(Mc), dim3(256), 0, stream>>>(
                ROWSA + base, V, 1, Mc, Cc, bias, q, CH, CC, LG);
        }
    }

    for (int i = 0; i < NL-1; ++i){
        k_step<<<dim3(NB), dim3(64), 0, stream>>>(i, len, H, Cc, CH, CC, LG, NXT, PRV, ROWS);
        if (i < NL-2){
            // refresh GEMM: M=256, K=1024 split x4 (k-chunks of 256), N=2560
            k_gemm<4,16><<<dim3(SROWS/64, NN/64, 4), dim3(256), 0, stream>>>(
                ROWS, SROWS, H, W, V);
            k_combine<<<dim3(SROWS), dim3(256), 0, stream>>>(
                ROWS, V, 4, SROWS, Cc, bias, q, CH, CC, LG);
        }
    }
    k_out<<<dim3(NB), dim3(128), 0, stream>>>(H, out);
}

// Round 3
// 1792.925 us; speedup vs baseline: 5.6606x; 1.3164x over previous
//
#include <hip/hip_runtime.h>
#include <cfloat>
#include <cmath>

#define NB 128
#define NL 48
#define HID 512
#define NSLOT 48
#define NN 2560              // 5*HID output cols
#define NNODE (NB*NSLOT)     // 6144
#define AROWS (NB*(NL-1))    // 6016 phase-A pair rows
#define SROWS (NB*2)         // 256 per-step refresh pairs

// ---------------- workspace layout (float units) ----------------
static const size_t offH    = 0;                                   // [B][48][512]
static const size_t offC    = offH  + (size_t)NNODE*HID;
static const size_t offCH   = offC  + (size_t)NNODE*HID;           // candidate h
static const size_t offCC   = offCH + (size_t)NNODE*HID;           // candidate c
static const size_t offLG   = offCC + (size_t)NNODE*HID;           // logits [B][48]
static const size_t offNXT  = offLG  + NNODE;                      // int
static const size_t offPRV  = offNXT + NNODE;                      // int
static const size_t offROWS = offPRV + NNODE;                      // int4 x 256
static const size_t offROWSA= offROWS + (size_t)4*SROWS;           // int4 x 6016
static const size_t offROWSN= offROWSA + (size_t)4*AROWS;          // int x 6144
static const size_t offPROW = offROWSN + NNODE;                    // int x 128
static const size_t offBIG  = offPROW + 128;
// new path: PL, PR each NNODE*NN floats (62.9MB)  -> total ~176.5 MB
// old path: V = 3072*NN floats (31.5MB)           -> total ~82 MB

__device__ __forceinline__ float sigf(float x){ return 1.0f/(1.0f+expf(-x)); }

// ---------------- init: copy input -> H,C ; init links/logits ----------------
__global__ void k_init(const float* __restrict__ in, const int* __restrict__ len,
                       float* __restrict__ H, float* __restrict__ Cc,
                       float* __restrict__ LG, int* __restrict__ NXT,
                       int* __restrict__ PRV, int4* __restrict__ ROWS)
{
    int bs = blockIdx.x;            // b*48+s
    int b  = bs / NSLOT, s = bs % NSLOT;
    int t  = threadIdx.x;           // 256 threads, 1 float4 each
    const float4* inrow = (const float4*)(in + (size_t)bs*2*HID);
    float4 v = inrow[t];
    if (t < 128) ((float4*)(H  + (size_t)bs*HID))[t]       = v;
    else         ((float4*)(Cc + (size_t)bs*HID))[t - 128] = v;
    if (t == 0) {
        int lb = len[b];
        NXT[bs] = (s+1 < lb) ? s+1 : -1;
        PRV[bs] = (s > 0 && s < lb) ? s-1 : -1;
        LG[bs]  = -FLT_MAX;
        if (s == 0) {
            ROWS[b*2+0] = make_int4(0,0,0,-1);
            ROWS[b*2+1] = make_int4(0,0,0,-1);
        }
    }
}

// ---------------- descriptors: pair rows (phase A) + node rows ----------------
__global__ void k_descA(const int* __restrict__ len, int4* __restrict__ ROWSA,
                        int* __restrict__ ROWSN)
{
    int r = blockIdx.x*256 + threadIdx.x;
    if (r < NNODE) ROWSN[r] = r;
    if (r >= AROWS) return;
    int b = r/(NL-1), s = r%(NL-1);
    int lb = len[b];
    ROWSA[r] = make_int4(b, s, s+1, (s <= lb-2) ? s : -1);
}

// ================= split-W path =================
// PL[node][n] = sum_k H[node][k]*W[n][k],  PR[node][n] = sum_k H[node][k]*W[n][512+k]
// Stacked as virtual N=5120: vn<2560 -> PL, else PR. BN=64 (block entirely one side).
template<int MI, int KT>
__global__ __launch_bounds__(256, 4)
void k_gemmP(const int* __restrict__ rows,
             const float* __restrict__ H, const float* __restrict__ W,
             float* __restrict__ PL, float* __restrict__ PR)
{
    constexpr int BM  = 16*MI;
    constexpr int AF4 = BM/64;
    constexpr int LDA = BM + 4;
    constexpr int LDB = 68;
    __shared__ float As[2][16*LDA];
    __shared__ float Bs[2][16*LDB];

    const int t   = threadIdx.x;
    const int m0  = blockIdx.x*BM;
    const int vn0 = blockIdx.y*64;
    const int side = (vn0 >= NN);
    const int n0  = side ? vn0 - NN : vn0;
    float* OUT = side ? PR : PL;

    int aoff[AF4], arow[AF4], aseg[AF4];
    #pragma unroll
    for (int j=0;j<AF4;++j){
        int f = t*AF4 + j;
        arow[j] = f >> 2; aseg[j] = f & 3;
        aoff[j] = rows[m0 + arow[j]]*HID + aseg[j]*4;
    }
    const int brow = t >> 2, bseg = t & 3;
    const float* wptr = W + (size_t)(n0 + brow)*1024 + side*HID + bseg*4;

    const int tm = t >> 4, tn = t & 15;

    float acc[MI][4];
    #pragma unroll
    for (int mi=0;mi<MI;++mi)
        #pragma unroll
        for (int j=0;j<4;++j) acc[mi][j]=0.f;

    float4 av[AF4], bv;
    auto gload = [&](int kt){
        int kg = kt*16;
        #pragma unroll
        for (int j=0;j<AF4;++j) av[j] = *(const float4*)(H + aoff[j] + kg);
        bv = *(const float4*)(wptr + kg);
    };
    auto swrite = [&](int buf){
        #pragma unroll
        for (int j=0;j<AF4;++j){
            As[buf][(aseg[j]*4+0)*LDA + arow[j]] = av[j].x;
            As[buf][(aseg[j]*4+1)*LDA + arow[j]] = av[j].y;
            As[buf][(aseg[j]*4+2)*LDA + arow[j]] = av[j].z;
            As[buf][(aseg[j]*4+3)*LDA + arow[j]] = av[j].w;
        }
        Bs[buf][(bseg*4+0)*LDB + brow] = bv.x;
        Bs[buf][(bseg*4+1)*LDB + brow] = bv.y;
        Bs[buf][(bseg*4+2)*LDB + brow] = bv.z;
        Bs[buf][(bseg*4+3)*LDB + brow] = bv.w;
    };

    gload(0); swrite(0); __syncthreads();

    for (int kt=0; kt<KT; ++kt){
        int buf = kt & 1;
        if (kt+1 < KT) gload(kt+1);
        #pragma unroll
        for (int k=0;k<16;++k){
            float a[MI];
            #pragma unroll
            for (int mi=0;mi<MI;mi+=4){
                float4 a4 = *(const float4*)&As[buf][k*LDA + tm*MI + mi];
                a[mi]=a4.x; a[mi+1]=a4.y; a[mi+2]=a4.z; a[mi+3]=a4.w;
            }
            float4 b4 = *(const float4*)&Bs[buf][k*LDB + tn*4];
            #pragma unroll
            for (int mi=0;mi<MI;++mi){
                acc[mi][0] = fmaf(a[mi], b4.x, acc[mi][0]);
                acc[mi][1] = fmaf(a[mi], b4.y, acc[mi][1]);
                acc[mi][2] = fmaf(a[mi], b4.z, acc[mi][2]);
                acc[mi][3] = fmaf(a[mi], b4.w, acc[mi][3]);
            }
        }
        if (kt+1 < KT) swrite(buf^1);
        __syncthreads();
    }

    #pragma unroll
    for (int mi=0;mi<MI;++mi){
        int row = m0 + tm*MI + mi;
        float4 o; o.x=acc[mi][0]; o.y=acc[mi][1]; o.z=acc[mi][2]; o.w=acc[mi][3];
        *(float4*)(OUT + (size_t)rows[row]*NN + n0 + tn*4) = o;
    }
}

// combine: v = PL[l] + PR[r] + bias -> LSTM epilogue -> CH/CC[dst] + logit -> LG
__global__ void k_combineP(const int4* __restrict__ rows,
                           const float* __restrict__ PL, const float* __restrict__ PR,
                           const float* __restrict__ Cc, const float* __restrict__ bias,
                           const float* __restrict__ q,
                           float* __restrict__ CH, float* __restrict__ CC,
                           float* __restrict__ LG)
{
    int4 rd = rows[blockIdx.x];
    if (rd.w < 0) return;
    int t = threadIdx.x;
    int b = rd.x, sl = rd.y, sr = rd.z, dst = rd.w;
    const float* pl = PL + (size_t)(b*NSLOT+sl)*NN;
    const float* pr = PR + (size_t)(b*NSLOT+sr)*NN;
    const float* cl = Cc + (size_t)(b*NSLOT+sl)*HID;
    const float* cr = Cc + (size_t)(b*NSLOT+sr)*HID;
    float part = 0.f;
    #pragma unroll
    for (int h2=0; h2<2; ++h2){
        int c = t + h2*256;
        float v[5];
        #pragma unroll
        for (int g=0; g<5; ++g)
            v[g] = pl[g*HID+c] + pr[g*HID+c] + bias[g*HID+c];
        float cn = cl[c]*sigf(v[1]+1.f) + cr[c]*sigf(v[2]+1.f) + tanhf(v[3])*sigf(v[0]);
        float hn = sigf(v[4])*tanhf(cn);
        CH[(size_t)(b*NSLOT+dst)*HID + c] = hn;
        CC[(size_t)(b*NSLOT+dst)*HID + c] = cn;
        part += q[c]*hn;
    }
    __shared__ float red[4];
    #pragma unroll
    for (int off=32; off; off>>=1) part += __shfl_xor(part, off);
    if ((t & 63) == 0) red[t>>6] = part;
    __syncthreads();
    if (t == 0) LG[b*NSLOT + dst] = red[0]+red[1]+red[2]+red[3];
}

// ================= fallback (round-2) GEMM path =================
template<int MI, int KT>
__global__ __launch_bounds__(256, 4)
void k_gemm(const int4* __restrict__ rows, int M,
            const float* __restrict__ H, const float* __restrict__ W,
            float* __restrict__ out)
{
    constexpr int BM  = 16*MI;
    constexpr int AF4 = BM/64;
    constexpr int LDA = BM + 4;
    constexpr int LDB = 68;
    __shared__ float As[2][16*LDA];
    __shared__ float Bs[2][16*LDB];

    const int t  = threadIdx.x;
    const int m0 = blockIdx.x*BM;
    const int n0 = blockIdx.y*64;
    const int kz = blockIdx.z;
    const int kg0 = kz*KT*16;

    int aoffL[AF4], aoffR[AF4], arow[AF4], aseg[AF4];
    #pragma unroll
    for (int j=0;j<AF4;++j){
        int f = t*AF4 + j;
        arow[j] = f >> 2; aseg[j] = f & 3;
        int4 rd = rows[m0 + arow[j]];
        aoffL[j] = (rd.x*NSLOT + rd.y)*HID + aseg[j]*4;
        aoffR[j] = (rd.x*NSLOT + rd.z)*HID + aseg[j]*4;
    }
    const int brow = t >> 2, bseg = t & 3;
    const float* wptr = W + (size_t)(n0 + brow)*1024 + bseg*4;
    const int tm = t >> 4, tn = t & 15;

    float acc[MI][4];
    #pragma unroll
    for (int mi=0;mi<MI;++mi)
        #pragma unroll
        for (int j=0;j<4;++j) acc[mi][j]=0.f;

    float4 av[AF4], bv;
    auto gload = [&](int kt){
        int kg = kg0 + kt*16;
        int sideR = (kg >> 9) & 1;
        int ke = kg & 511;
        #pragma unroll
        for (int j=0;j<AF4;++j)
            av[j] = *(const float4*)(H + (sideR ? aoffR[j] : aoffL[j]) + ke);
        bv = *(const float4*)(wptr + kg);
    };
    auto swrite = [&](int buf){
        #pragma unroll
        for (int j=0;j<AF4;++j){
            As[buf][(aseg[j]*4+0)*LDA + arow[j]] = av[j].x;
            As[buf][(aseg[j]*4+1)*LDA + arow[j]] = av[j].y;
            As[buf][(aseg[j]*4+2)*LDA + arow[j]] = av[j].z;
            As[buf][(aseg[j]*4+3)*LDA + arow[j]] = av[j].w;
        }
        Bs[buf][(bseg*4+0)*LDB + brow] = bv.x;
        Bs[buf][(bseg*4+1)*LDB + brow] = bv.y;
        Bs[buf][(bseg*4+2)*LDB + brow] = bv.z;
        Bs[buf][(bseg*4+3)*LDB + brow] = bv.w;
    };

    gload(0); swrite(0); __syncthreads();

    for (int kt=0; kt<KT; ++kt){
        int buf = kt & 1;
        if (kt+1 < KT) gload(kt+1);
        #pragma unroll
        for (int k=0;k<16;++k){
            float a[MI];
            #pragma unroll
            for (int mi=0;mi<MI;mi+=4){
                float4 a4 = *(const float4*)&As[buf][k*LDA + tm*MI + mi];
                a[mi]=a4.x; a[mi+1]=a4.y; a[mi+2]=a4.z; a[mi+3]=a4.w;
            }
            float4 b4 = *(const float4*)&Bs[buf][k*LDB + tn*4];
            #pragma unroll
            for (int mi=0;mi<MI;++mi){
                acc[mi][0] = fmaf(a[mi], b4.x, acc[mi][0]);
                acc[mi][1] = fmaf(a[mi], b4.y, acc[mi][1]);
                acc[mi][2] = fmaf(a[mi], b4.z, acc[mi][2]);
                acc[mi][3] = fmaf(a[mi], b4.w, acc[mi][3]);
            }
        }
        if (kt+1 < KT) swrite(buf^1);
        __syncthreads();
    }

    #pragma unroll
    for (int mi=0;mi<MI;++mi){
        int row = m0 + tm*MI + mi;
        float4 o; o.x=acc[mi][0]; o.y=acc[mi][1]; o.z=acc[mi][2]; o.w=acc[mi][3];
        *(float4*)(out + (size_t)(kz*M + row)*NN + n0 + tn*4) = o;
    }
}

__global__ void k_combine(const int4* __restrict__ rows, const float* __restrict__ V,
                          int KS, int M,
                          const float* __restrict__ Cc, const float* __restrict__ bias,
                          const float* __restrict__ q,
                          float* __restrict__ CH, float* __restrict__ CC,
                          float* __restrict__ LG)
{
    int r = blockIdx.x;
    int4 rd = rows[r];
    if (rd.w < 0) return;
    int t = threadIdx.x;
    int b = rd.x, sl = rd.y, sr = rd.z, dst = rd.w;
    const float* cl = Cc + (size_t)(b*NSLOT+sl)*HID;
    const float* cr = Cc + (size_t)(b*NSLOT+sr)*HID;
    float part = 0.f;
    #pragma unroll
    for (int h2=0; h2<2; ++h2){
        int c = t + h2*256;
        float v[5];
        #pragma unroll
        for (int g=0; g<5; ++g){
            float s = bias[g*HID + c];
            for (int kzi=0; kzi<KS; ++kzi)
                s += V[(size_t)(kzi*M + r)*NN + g*HID + c];
            v[g] = s;
        }
        float cn = cl[c]*sigf(v[1]+1.f) + cr[c]*sigf(v[2]+1.f) + tanhf(v[3])*sigf(v[0]);
        float hn = sigf(v[4])*tanhf(cn);
        CH[(size_t)(b*NSLOT+dst)*HID + c] = hn;
        CC[(size_t)(b*NSLOT+dst)*HID + c] = cn;
        part += q[c]*hn;
    }
    __shared__ float red[4];
    #pragma unroll
    for (int off=32; off; off>>=1) part += __shfl_xor(part, off);
    if ((t & 63) == 0) red[t>>6] = part;
    __syncthreads();
    if (t == 0) LG[b*NSLOT + dst] = red[0]+red[1]+red[2]+red[3];
}

// ---------------- per-step: argmax, commit, relink ----------------
__global__ void k_step(int i, const int* __restrict__ len,
                       float* __restrict__ H, float* __restrict__ Cc,
                       const float* __restrict__ CH, const float* __restrict__ CC,
                       float* __restrict__ LG, int* __restrict__ NXT,
                       int* __restrict__ PRV, int4* __restrict__ ROWS,
                       int* __restrict__ PROW)
{
    int b = blockIdx.x, lane = threadIdx.x;   // block = 64 = 1 wave
    int base = b*NSLOT;
    int lb = len[b];
    if (i > lb-2){
        if (lane==0){
            ROWS[b*2+0]=make_int4(0,0,0,-1); ROWS[b*2+1]=make_int4(0,0,0,-1);
            PROW[b] = base;                   // recompute slot 0 (benign)
        }
        return;
    }

    // argmax over slots (first-max => smallest slot on tie)
    float val = (lane < NSLOT) ? LG[base+lane] : -FLT_MAX;
    int idx = lane;
    for (int off=1; off<64; off<<=1){
        float oval = __shfl_xor(val, off);
        int   oidx = __shfl_xor(idx, off);
        if (oval > val || (oval == val && oidx < idx)){ val = oval; idx = oidx; }
    }
    int sstar = idx;
    int r  = NXT[base+sstar];
    int qn = NXT[base+r];
    int p  = PRV[base+sstar];

    // commit merged node into left child's slot
    const float4* sh = (const float4*)(CH + (size_t)(base+sstar)*HID);
    const float4* sc = (const float4*)(CC + (size_t)(base+sstar)*HID);
    float4* dh = (float4*)(H  + (size_t)(base+sstar)*HID);
    float4* dc = (float4*)(Cc + (size_t)(base+sstar)*HID);
    dh[lane] = sh[lane]; dh[lane+64] = sh[lane+64];
    dc[lane] = sc[lane]; dc[lane+64] = sc[lane+64];

    // relink + invalidate + emit refresh rows
    if (lane==0){
        NXT[base+sstar] = qn;
        if (qn >= 0) PRV[base+qn] = sstar;
        LG[base+r] = -FLT_MAX;
        if (qn < 0) LG[base+sstar] = -FLT_MAX;
        ROWS[b*2+0] = (p  >= 0) ? make_int4(b, p, sstar, p)      : make_int4(0,0,0,-1);
        ROWS[b*2+1] = (qn >= 0) ? make_int4(b, sstar, qn, sstar) : make_int4(0,0,0,-1);
        PROW[b] = base + sstar;
    }
}

// ---------------- output: root = slot 0 ----------------
__global__ void k_out(const float* __restrict__ H, float* __restrict__ out)
{
    int b = blockIdx.x, t = threadIdx.x;       // 128 threads x float4
    ((float4*)out)[b*128 + t] = ((const float4*)(H + (size_t)b*NSLOT*HID))[t];
}

extern "C" void kernel_launch(void* const* d_in, const int* in_sizes, int n_in,
                              void* d_out, int out_size, void* d_ws, size_t ws_size,
                              hipStream_t stream)
{
    const float* in   = (const float*)d_in[0];
    const float* W    = (const float*)d_in[1];
    const float* bias = (const float*)d_in[2];
    const float* q    = (const float*)d_in[3];
    const int*   len  = (const int*)d_in[4];

    float* ws = (float*)d_ws;
    float* H  = ws + offH;
    float* Cc = ws + offC;
    float* CH = ws + offCH;
    float* CC = ws + offCC;
    float* LG = ws + offLG;
    int* NXT  = (int*)(ws + offNXT);
    int* PRV  = (int*)(ws + offPRV);
    int4* ROWS  = (int4*)(ws + offROWS);
    int4* ROWSA = (int4*)(ws + offROWSA);
    int*  ROWSN = (int*)(ws + offROWSN);
    int*  PROW  = (int*)(ws + offPROW);
    float* out = (float*)d_out;

    const size_t needBig = (offBIG + 2*(size_t)NNODE*NN) * sizeof(float);
    const bool big = (ws_size >= needBig);

    k_init <<<dim3(NNODE), dim3(256), 0, stream>>>(in, len, H, Cc, LG, NXT, PRV, ROWS);
    k_descA<<<dim3(NNODE/256), dim3(256), 0, stream>>>(len, ROWSA, ROWSN);

    if (big){
        float* PL = ws + offBIG;
        float* PR = PL + (size_t)NNODE*NN;
        // phase A: per-node products, then pair-combine
        k_gemmP<8,32><<<dim3(NNODE/128, 2*NN/64), dim3(256), 0, stream>>>(ROWSN, H, W, PL, PR);
        k_combineP<<<dim3(AROWS), dim3(256), 0, stream>>>(ROWSA, PL, PR, Cc, bias, q, CH, CC, LG);

        for (int i = 0; i < NL-1; ++i){
            k_step<<<dim3(NB), dim3(64), 0, stream>>>(i, len, H, Cc, CH, CC, LG, NXT, PRV, ROWS, PROW);
            if (i < NL-2){
                k_gemmP<4,32><<<dim3(NB/64, 2*NN/64), dim3(256), 0, stream>>>(PROW, H, W, PL, PR);
                k_combineP<<<dim3(SROWS), dim3(256), 0, stream>>>(ROWS, PL, PR, Cc, bias, q, CH, CC, LG);
            }
        }
    } else {
        float* V = ws + offBIG;
        int bases[3] = {0, 3072, AROWS};
        for (int c2 = 0; c2 < 2; ++c2){
            int base = bases[c2], Mc = bases[c2+1] - base;
            k_gemm<8,64><<<dim3(Mc/128, NN/64, 1), dim3(256), 0, stream>>>(ROWSA + base, Mc, H, W, V);
            k_combine<<<dim3(Mc), dim3(256), 0, stream>>>(ROWSA + base, V, 1, Mc, Cc, bias, q, CH, CC, LG);
        }
        for (int i = 0; i < NL-1; ++i){
            k_step<<<dim3(NB), dim3(64), 0, stream>>>(i, len, H, Cc, CH, CC, LG, NXT, PRV, ROWS, PROW);
            if (i < NL-2){
                k_gemm<4,16><<<dim3(SROWS/64, NN/64, 4), dim3(256), 0, stream>>>(ROWS, SROWS, H, W, V);
                k_combine<<<dim3(SROWS), dim3(256), 0, stream>>>(ROWS, V, 4, SROWS, Cc, bias, q, CH, CC, LG);
            }
        }
    }
    k_out<<<dim3(NB), dim3(128), 0, stream>>>(H, out);
}